// Round 12
// baseline (125.766 us; speedup 1.0000x reference)
//
#include <hip/hip_runtime.h>

typedef _Float16 half_t;
typedef _Float16 hx8 __attribute__((ext_vector_type(8)));
typedef _Float16 hx4 __attribute__((ext_vector_type(4)));
typedef float fx4 __attribute__((ext_vector_type(4)));

#define LOG2E 1.44269504088896f
#define TAU 0.1f
#define NSPLIT 8

// ---------------- Kernel 0: pack W1/W2 into fp16 A-fragment order ----------
// (unchanged — verified)
__global__ __launch_bounds__(256) void wpack_kernel(
    const float* __restrict__ W1, const float* __restrict__ W2,
    half_t* __restrict__ Wh1, half_t* __restrict__ Wh2)
{
  const int job = blockIdx.x*256 + threadIdx.x;   // 0..4095
  const int lane = job & 63;
  const int frag = (job >> 6) & 31;               // mt*4 + ks
  const int mat  = job >> 11;
  const int mt = frag >> 2, ks = frag & 3;
  const int q = lane >> 4, c = lane & 15;
  const float* W = mat ? W2 : W1;
  half_t* Wh = mat ? Wh2 : Wh1;
  hx8 v;
#pragma unroll
  for (int j=0;j<8;++j)
    v[j] = (half_t)W[(size_t)(ks*32 + q*8 + j)*128 + mt*16 + c];
  *(hx8*)(Wh + ((size_t)frag*64 + lane)*8) = v;
}

// ---------------- Kernel 1: fused ztrans + MLP (packed W frags) ------------
// (R6/R8 form — verified; mlpz variants are perf-insensitive, keep simplest)
__global__ __launch_bounds__(256) void mlpz_kernel(
    const float* __restrict__ Z, const half_t* __restrict__ Wh1,
    const float* __restrict__ b1, const half_t* __restrict__ Wh2,
    const float* __restrict__ b2, half_t* __restrict__ T,
    half_t* __restrict__ Zth)
{
  __shared__ float Ztile[16*132];       // 8.45 KB
  __shared__ half_t Hs[16*136];         // 4.35 KB
  const int tid = threadIdx.x;
  const int w = tid >> 6, lane = tid & 63;
  const int q = lane >> 4, c = lane & 15;
  const int rb = blockIdx.x*16;

#pragma unroll
  for (int i=0;i<2;++i) {
    int fid = i*256 + tid;
    int r = fid >> 5, c4 = (fid & 31)*4;
    *(fx4*)(&Ztile[r*132 + c4]) = *(const fx4*)(Z + (size_t)(rb + r)*128 + c4);
  }
  __syncthreads();

  {
    const int d = tid >> 1, h = tid & 1;  // paired: 2 threads per d-row
    hx8 hv;
#pragma unroll
    for (int u=0;u<8;++u) hv[u] = (half_t)Ztile[(h*8 + u)*132 + d];
    *(hx8*)(Zth + (size_t)d*8192 + rb + h*8) = hv;
  }

  hx8 zb[4];
#pragma unroll
  for (int ks=0;ks<4;++ks) {
    fx4 a = *(const fx4*)(&Ztile[c*132 + ks*32 + q*8]);
    fx4 b = *(const fx4*)(&Ztile[c*132 + ks*32 + q*8 + 4]);
#pragma unroll
    for (int u=0;u<4;++u) { zb[ks][u] = (half_t)a[u]; zb[ks][4+u] = (half_t)b[u]; }
  }

  // ---- layer 1: wave w owns mt = 2w, 2w+1 ----
#pragma unroll
  for (int m2=0;m2<2;++m2) {
    const int mt = w*2 + m2;
    fx4 acc = (fx4){0.f,0.f,0.f,0.f};
#pragma unroll
    for (int ks=0;ks<4;++ks) {
      hx8 aw = *(const hx8*)(Wh1 + ((size_t)(mt*4 + ks)*64 + lane)*8);
      acc = __builtin_amdgcn_mfma_f32_16x16x32_f16(aw, zb[ks], acc, 0,0,0);
    }
    fx4 bias = *(const fx4*)(b1 + mt*16 + 4*q);
    hx4 hv;
#pragma unroll
    for (int i=0;i<4;++i) {
      float h = acc[i] + bias[i];
      hv[i] = (half_t)(h > 0.f ? h : 0.f);
    }
    *(hx4*)(&Hs[c*136 + mt*16 + 4*q]) = hv;
  }
  __syncthreads();

  // ---- layer 2 ----
  hx8 hb[4];
#pragma unroll
  for (int ks=0;ks<4;++ks) hb[ks] = *(const hx8*)(&Hs[c*136 + ks*32 + q*8]);
#pragma unroll
  for (int m2=0;m2<2;++m2) {
    const int mt = w*2 + m2;
    fx4 acc = (fx4){0.f,0.f,0.f,0.f};
#pragma unroll
    for (int ks=0;ks<4;++ks) {
      hx8 aw = *(const hx8*)(Wh2 + ((size_t)(mt*4 + ks)*64 + lane)*8);
      acc = __builtin_amdgcn_mfma_f32_16x16x32_f16(aw, hb[ks], acc, 0,0,0);
    }
    fx4 bias = *(const fx4*)(b2 + mt*16 + 4*q);
    hx4 tv;
#pragma unroll
    for (int i=0;i<4;++i) tv[i] = (half_t)(acc[i] + bias[i]);
    *(hx4*)(T + (size_t)(rb + c)*128 + mt*16 + 4*q) = tv;
  }
}

// ---------------- Kernel 2: flash attention partials (R8 + T5 setprio) -----
// R8 proven best (55.1-55.6us): 64-key tiles, nt=2, grid 512, deferred
// l-sum, max3 tree, per-wave private Pbuf, 1 barrier/iter, full-iteration
// prefetch. Round-12 change ONLY: s_setprio(1/0) around the two MFMA
// clusters. T5's regime (waves at DIFFERENT phases) now holds: 1 barrier +
// wave-private P means the 8 waves/CU drift apart within an iteration, so
// the scheduler can favor MFMA-entering waves over softmax-VALU waves.
// Zero footprint change (no VGPR/LDS delta).
// Lessons ledger: (1) >=64-key tiles (R2); (2) occupancy-by-restructure
// 0-for-4 (R1,R2,R3,R9); (3) ALL MFMA operands in lgkmcnt domain — global
// loads + prefetch DMA in one vmcnt FIFO across a conditional forces
// vmcnt(0), drains prefetch (R1,R9); (4) T13 defer-max HURT (R4);
// (5) deferred l-sum WIN (R6: -2.8us); (6) v_pk_f32 on live accs -> spill
// cliff (R7); (7) P^T rows 128B, sw=(c&7)*8; (8) NEVER
// __launch_bounds__(256,3+); (9) barrier count NOT the cost (R8 neutral);
// (10) mlpz compute NOT the cost (R10); (11) cooperative launch silently
// no-ops under harness capture -> output zeros (R11); (12) launch COUNT not
// the cost either (R0 3-launch vs R4 4-launch: equal "other").
__global__ __launch_bounds__(256,2) void flash_kernel(
    const half_t* __restrict__ T, const half_t* __restrict__ Zt,
    half_t* __restrict__ Pacc, float* __restrict__ Pm, float* __restrict__ Pl)
{
  __shared__ half_t Tbuf[2][16*512];    // 32 KB
  __shared__ half_t Zbuf[2][16*512];    // 32 KB
  __shared__ half_t Pbuf[4][32*64];     // 16 KB — per-wave private P^T
  const int tid = threadIdx.x;
  const int w = tid >> 6, lane = tid & 63;
  const int q = lane >> 4, c = lane & 15;
  const int bx = blockIdx.x;
  const int qb = bx >> 3, kh = bx & 7;
  const int wrow = qb*128 + w*32;
  const int sw = (c & 7) * 8;

  hx8 bq[2][4];
#pragma unroll
  for (int nt=0;nt<2;++nt)
#pragma unroll
    for (int ks=0;ks<4;++ks)
      bq[nt][ks] = *(const hx8*)(T + (size_t)(wrow + nt*16 + c)*128 + ks*32 + q*8);

  fx4 oacc[8][2];
#pragma unroll
  for (int mtd=0;mtd<8;++mtd)
#pragma unroll
    for (int nt=0;nt<2;++nt) oacc[mtd][nt] = (fx4){0.f,0.f,0.f,0.f};
  float m_run[2] = {-1e30f,-1e30f};
  float l_run[2] = {0.f,0.f};          // per-lane PARTIAL sums (reduced at end)

  const int kbase = kh*1024;
  half_t* Psw = &Pbuf[w][0];           // wave-private 32x64-half P^T

  auto issue_loads = [&](int kt0, int b) {
    if (w < 2) {
#pragma unroll
      for (int i=0;i<8;++i) {
        int f = w*8 + i, mt = f >> 2, ks = f & 3;
        const half_t* gp = T + (size_t)(kt0 + mt*16 + c)*128 + ks*32 + q*8;
        half_t* lp = &Tbuf[b][f*512 + lane*8];
        __builtin_amdgcn_global_load_lds(
            (const __attribute__((address_space(1))) void*)gp,
            (__attribute__((address_space(3))) void*)lp, 16, 0, 0);
      }
    } else {
#pragma unroll
      for (int i=0;i<8;++i) {
        int f2 = (w-2)*8 + i, mtd = f2 >> 1, ks2 = f2 & 1;
        const half_t* gp = Zt + (size_t)(mtd*16 + c)*8192 + kt0 + ks2*32 + q*8;
        half_t* lp = &Zbuf[b][f2*512 + lane*8];
        __builtin_amdgcn_global_load_lds(
            (const __attribute__((address_space(1))) void*)gp,
            (__attribute__((address_space(3))) void*)lp, 16, 0, 0);
      }
    }
  };

  issue_loads(kbase, 0);

  for (int t=0;t<16;++t) {
    const int cur = t & 1;
    __syncthreads();                    // THE barrier: drains own DMA (vmcnt)
                                        // + publishes both buffers of iter t
    half_t* Tcur = Tbuf[cur];
    half_t* Zcur = Zbuf[cur];

    // prefetch t+1 NOW: cur^1 is dead (barrier retired all t-1 reads)
    if (t < 15) issue_loads(kbase + (t+1)*64, cur ^ 1);

    // ---- scores ----
    fx4 sacc[4][2];
#pragma unroll
    for (int mt=0;mt<4;++mt)
#pragma unroll
      for (int nt=0;nt<2;++nt) sacc[mt][nt] = (fx4){0.f,0.f,0.f,0.f};
    __builtin_amdgcn_s_setprio(1);      // T5: favor MFMA-entering wave
#pragma unroll
    for (int ks=0;ks<4;++ks)
#pragma unroll
      for (int mt=0;mt<4;++mt) {
        hx8 ak = *(const hx8*)(&Tcur[(mt*4+ks)*512 + lane*8]);
        sacc[mt][0] = __builtin_amdgcn_mfma_f32_16x16x32_f16(ak, bq[0][ks], sacc[mt][0], 0,0,0);
        sacc[mt][1] = __builtin_amdgcn_mfma_f32_16x16x32_f16(ak, bq[1][ks], sacc[mt][1], 0,0,0);
      }
    __builtin_amdgcn_s_setprio(0);

    // ---- online softmax (per-lane partial l; only the MAX is shfl'd) ----
    hx4 pk[2][4];
#pragma unroll
    for (int nt=0;nt<2;++nt) {
      float a0 = fmaxf(fmaxf(sacc[0][nt][0], sacc[0][nt][1]), sacc[0][nt][2]);
      float a1 = fmaxf(fmaxf(sacc[0][nt][3], sacc[1][nt][0]), sacc[1][nt][1]);
      float a2 = fmaxf(fmaxf(sacc[1][nt][2], sacc[1][nt][3]), sacc[2][nt][0]);
      float a3 = fmaxf(fmaxf(sacc[2][nt][1], sacc[2][nt][2]), sacc[2][nt][3]);
      float a4 = fmaxf(fmaxf(sacc[3][nt][0], sacc[3][nt][1]), sacc[3][nt][2]);
      float mx = fmaxf(fmaxf(fmaxf(a0, a1), fmaxf(a2, a3)),
                       fmaxf(a4, sacc[3][nt][3]));
      mx = fmaxf(mx, __shfl_xor(mx, 16, 64));
      mx = fmaxf(mx, __shfl_xor(mx, 32, 64));
      float mnew = fmaxf(m_run[nt], mx);
      float alpha = __builtin_amdgcn_exp2f((m_run[nt]-mnew)*LOG2E);
      m_run[nt] = mnew;
      float nb = mnew*LOG2E;
      float rs = 0.f;
#pragma unroll
      for (int mt=0;mt<4;++mt) {
#pragma unroll
        for (int i=0;i<4;++i) {
          float p = __builtin_amdgcn_exp2f(sacc[mt][nt][i]*LOG2E - nb);
          rs += p;
          pk[nt][mt][i] = (half_t)p;
        }
      }
      l_run[nt] = l_run[nt]*alpha + rs;   // per-lane partial (no shfl here)
#pragma unroll
      for (int mtd=0;mtd<8;++mtd)
#pragma unroll
        for (int i=0;i<4;++i) oacc[mtd][nt][i] *= alpha;
    }

    // P^T into wave-private region (no inter-wave race -> NO barrier)
#pragma unroll
    for (int nt=0;nt<2;++nt)
#pragma unroll
      for (int mt=0;mt<4;++mt)
        *(hx4*)(&Psw[(nt*16 + c)*64 + ((mt*16 + 4*q) ^ sw)]) = pk[nt][mt];

    // ---- PV ----
    __builtin_amdgcn_s_setprio(1);      // T5
#pragma unroll
    for (int ks2=0;ks2<2;++ks2) {
      hx8 bp0 = *(const hx8*)(&Psw[(c     )*64 + ((ks2*32 + q*8) ^ sw)]);
      hx8 bp1 = *(const hx8*)(&Psw[(16 + c)*64 + ((ks2*32 + q*8) ^ sw)]);
#pragma unroll
      for (int mtd=0;mtd<8;++mtd) {
        hx8 az = *(const hx8*)(&Zcur[(mtd*2+ks2)*512 + lane*8]);
        oacc[mtd][0] = __builtin_amdgcn_mfma_f32_16x16x32_f16(az, bp0, oacc[mtd][0], 0,0,0);
        oacc[mtd][1] = __builtin_amdgcn_mfma_f32_16x16x32_f16(az, bp1, oacc[mtd][1], 0,0,0);
      }
    }
    __builtin_amdgcn_s_setprio(0);
  }

  // epilogue: reduce the deferred l partials across the 4 lanes per q-row
#pragma unroll
  for (int nt=0;nt<2;++nt) {
    float lf = l_run[nt];
    lf += __shfl_xor(lf, 16, 64);
    lf += __shfl_xor(lf, 32, 64);
    float inv = 1.0f / lf;
    const size_t rowg = (size_t)(bx*128 + w*32 + nt*16 + c);
#pragma unroll
    for (int mtd=0;mtd<8;++mtd) {
      hx4 ov;
#pragma unroll
      for (int i=0;i<4;++i) ov[i] = (half_t)(oacc[mtd][nt][i]*inv);
      *(hx4*)(Pacc + rowg*128 + mtd*16 + 4*q) = ov;
    }
    if (q == 0) {
      Pm[rowg] = m_run[nt];
      Pl[rowg] = lf;
    }
  }
}

// ---------------- Kernel 3: merge NSPLIT key-split partials ----------------
// (unchanged)
__global__ __launch_bounds__(256) void merge_kernel(
    const float* __restrict__ Z, const half_t* __restrict__ Pacc,
    const float* __restrict__ Pm, const float* __restrict__ Pl,
    float* __restrict__ out)
{
  const int th = blockIdx.x*256 + threadIdx.x;
  const int r = th >> 5, cg = th & 31;
  const int qb = r >> 7, rr = r & 127;
  float mk[NSPLIT], lk[NSPLIT];
  float M = -1e30f;
#pragma unroll
  for (int k=0;k<NSPLIT;++k) {
    int p = qb*NSPLIT + k;
    mk[k] = Pm[p*128 + rr];
    lk[k] = Pl[p*128 + rr];
    M = fmaxf(M, mk[k]);
  }
  float L = 0.f, wk[NSPLIT];
#pragma unroll
  for (int k=0;k<NSPLIT;++k) { wk[k] = lk[k]*__builtin_amdgcn_exp2f((mk[k]-M)*LOG2E); L += wk[k]; }
  float o0=0.f,o1=0.f,o2=0.f,o3=0.f;
#pragma unroll
  for (int k=0;k<NSPLIT;++k) {
    int p = qb*NSPLIT + k;
    hx4 v = *(const hx4*)(Pacc + ((size_t)p*128 + rr)*128 + cg*4);
    o0 += wk[k]*(float)v[0]; o1 += wk[k]*(float)v[1];
    o2 += wk[k]*(float)v[2]; o3 += wk[k]*(float)v[3];
  }
  float invL = 1.0f / L;
  fx4 zv = *(const fx4*)(Z + (size_t)r*128 + cg*4);
  fx4 res;
  res[0] = (1.f-TAU)*zv[0] + TAU*o0*invL;
  res[1] = (1.f-TAU)*zv[1] + TAU*o1*invL;
  res[2] = (1.f-TAU)*zv[2] + TAU*o2*invL;
  res[3] = (1.f-TAU)*zv[3] + TAU*o3*invL;
  *(fx4*)(out + (size_t)r*128 + cg*4) = res;
}

extern "C" void kernel_launch(void* const* d_in, const int* in_sizes, int n_in,
                              void* d_out, int out_size, void* d_ws, size_t ws_size,
                              hipStream_t stream) {
  const float* Z  = (const float*)d_in[0];
  const float* W1 = (const float*)d_in[1];
  const float* b1 = (const float*)d_in[2];
  const float* W2 = (const float*)d_in[3];
  const float* b2 = (const float*)d_in[4];
  float* out = (float*)d_out;

  char* ws = (char*)d_ws;
  const size_t NBLK = 64 * NSPLIT;                                // 512
  half_t* Thi  = (half_t*)(ws);                                   // 2 MB
  half_t* Zth  = (half_t*)(ws + (size_t)2*1024*1024);             // 2 MB
  half_t* Pacc = (half_t*)(ws + (size_t)4*1024*1024);             // 16 MB
  float*  Pm   = (float*)(ws + (size_t)4*1024*1024 + NBLK*128*128*2);
  float*  Pl   = Pm + NBLK*128;
  half_t* Wh1  = (half_t*)(ws + (size_t)20*1024*1024 + 512*1024); // 32 KB
  half_t* Wh2  = Wh1 + 32*64*8;                                   // 32 KB

  hipLaunchKernelGGL(wpack_kernel, dim3(16),   dim3(256), 0, stream, W1, W2, Wh1, Wh2);
  hipLaunchKernelGGL(mlpz_kernel,  dim3(512),  dim3(256), 0, stream, Z, Wh1, b1, Wh2, b2, Thi, Zth);
  hipLaunchKernelGGL(flash_kernel, dim3(NBLK), dim3(256), 0, stream, Thi, Zth, Pacc, Pm, Pl);
  hipLaunchKernelGGL(merge_kernel, dim3(1024), dim3(256), 0, stream, Z, Pacc, Pm, Pl, out);
}

// Round 13
// 121.962 us; speedup vs baseline: 1.0312x; 1.0312x over previous
//
#include <hip/hip_runtime.h>

typedef _Float16 half_t;
typedef _Float16 hx8 __attribute__((ext_vector_type(8)));
typedef _Float16 hx4 __attribute__((ext_vector_type(4)));
typedef float fx4 __attribute__((ext_vector_type(4)));

#define LOG2E 1.44269504088896f
#define TAU 0.1f
#define NSPLIT 8

// ============================ SESSION SUMMARY ==============================
// Best measured build (R8): total 122.5us (baseline 129.6). flash 55.1-55.6.
// WINS: wpack+vector W frags (R4, enabler); deferred l-sum epilogue
// reduction (R6: flash 58.4->55.6); per-wave-private P + 1 barrier/iter +
// full-iteration prefetch (R8: neutral time, enables simpler schedule).
// Lessons ledger (all measured, one change per round):
//  (1) >=64-key tiles — halving tile doubles per-iter softmax aux (R2 +20%)
//  (2) occupancy-by-restructure 0-for-4 (R1,R2,R3,R9) — extra waves just
//      queue on the LDS pipe or lose operand reuse
//  (3) ALL MFMA operands in lgkmcnt domain; global loads + prefetch DMA in
//      one vmcnt FIFO across a conditional forces vmcnt(0) -> drains
//      prefetch (R1: 156us, R9: 160us, VGPR=84 = az not held)
//  (4) T13 defer-max HURT (R4: +3.6us — rescale too cheap to defer)
//  (5) deferred l-sum WIN (R6: -2.8us — serial shfl latency is exposed at
//      2 waves/SIMD)
//  (6) hand v_pk_f32 on live accumulators -> 128-VGPR cliff + scratch
//      spills (R7: +4.6us, FETCH/WRITE +3.4MB)
//  (7) P^T rows 128B with sw=(c&7)*8 xor-swizzle (R2: 64B rows -> 8-way
//      ds_write conflicts, 3.67M cycles)
//  (8) NEVER __launch_bounds__(256,3+)
//  (9) barrier count NOT the cost (R8 neutral)
// (10) mlpz compute NOT the cost (5 variants insensitive; "other" ~68us is
//      harness reset/replay + small-kernel tails)
// (11) hipLaunchCooperativeKernel silently no-ops under harness capture ->
//      zero output (R11)
// (12) launch COUNT not the cost (R0 3-launch == R4 4-launch "other")
// (13) s_setprio on this structure: -3us, codegen perturbation (R12,
//      VGPR 124->108)
// Plateau diagnosis: flash is latency-bound at 2 blocks/CU (MFMA 24% +
// VALU 33%, rest dep-chain stalls). Escapes would need 3-deep LDS buffering
// (>160KB at this tile) or reg-held V (forbidden by (3)).
// ===========================================================================

// ---------------- Kernel 0: pack W1/W2 into fp16 A-fragment order ----------
__global__ __launch_bounds__(256) void wpack_kernel(
    const float* __restrict__ W1, const float* __restrict__ W2,
    half_t* __restrict__ Wh1, half_t* __restrict__ Wh2)
{
  const int job = blockIdx.x*256 + threadIdx.x;   // 0..4095
  const int lane = job & 63;
  const int frag = (job >> 6) & 31;               // mt*4 + ks
  const int mat  = job >> 11;
  const int mt = frag >> 2, ks = frag & 3;
  const int q = lane >> 4, c = lane & 15;
  const float* W = mat ? W2 : W1;
  half_t* Wh = mat ? Wh2 : Wh1;
  hx8 v;
#pragma unroll
  for (int j=0;j<8;++j)
    v[j] = (half_t)W[(size_t)(ks*32 + q*8 + j)*128 + mt*16 + c];
  *(hx8*)(Wh + ((size_t)frag*64 + lane)*8) = v;
}

// ---------------- Kernel 1: fused ztrans + MLP (packed W frags) ------------
__global__ __launch_bounds__(256) void mlpz_kernel(
    const float* __restrict__ Z, const half_t* __restrict__ Wh1,
    const float* __restrict__ b1, const half_t* __restrict__ Wh2,
    const float* __restrict__ b2, half_t* __restrict__ T,
    half_t* __restrict__ Zth)
{
  __shared__ float Ztile[16*132];       // 8.45 KB
  __shared__ half_t Hs[16*136];         // 4.35 KB
  const int tid = threadIdx.x;
  const int w = tid >> 6, lane = tid & 63;
  const int q = lane >> 4, c = lane & 15;
  const int rb = blockIdx.x*16;

#pragma unroll
  for (int i=0;i<2;++i) {
    int fid = i*256 + tid;
    int r = fid >> 5, c4 = (fid & 31)*4;
    *(fx4*)(&Ztile[r*132 + c4]) = *(const fx4*)(Z + (size_t)(rb + r)*128 + c4);
  }
  __syncthreads();

  {
    const int d = tid >> 1, h = tid & 1;  // paired: 2 threads per d-row
    hx8 hv;
#pragma unroll
    for (int u=0;u<8;++u) hv[u] = (half_t)Ztile[(h*8 + u)*132 + d];
    *(hx8*)(Zth + (size_t)d*8192 + rb + h*8) = hv;
  }

  hx8 zb[4];
#pragma unroll
  for (int ks=0;ks<4;++ks) {
    fx4 a = *(const fx4*)(&Ztile[c*132 + ks*32 + q*8]);
    fx4 b = *(const fx4*)(&Ztile[c*132 + ks*32 + q*8 + 4]);
#pragma unroll
    for (int u=0;u<4;++u) { zb[ks][u] = (half_t)a[u]; zb[ks][4+u] = (half_t)b[u]; }
  }

  // ---- layer 1: wave w owns mt = 2w, 2w+1 ----
#pragma unroll
  for (int m2=0;m2<2;++m2) {
    const int mt = w*2 + m2;
    fx4 acc = (fx4){0.f,0.f,0.f,0.f};
#pragma unroll
    for (int ks=0;ks<4;++ks) {
      hx8 aw = *(const hx8*)(Wh1 + ((size_t)(mt*4 + ks)*64 + lane)*8);
      acc = __builtin_amdgcn_mfma_f32_16x16x32_f16(aw, zb[ks], acc, 0,0,0);
    }
    fx4 bias = *(const fx4*)(b1 + mt*16 + 4*q);
    hx4 hv;
#pragma unroll
    for (int i=0;i<4;++i) {
      float h = acc[i] + bias[i];
      hv[i] = (half_t)(h > 0.f ? h : 0.f);
    }
    *(hx4*)(&Hs[c*136 + mt*16 + 4*q]) = hv;
  }
  __syncthreads();

  // ---- layer 2 ----
  hx8 hb[4];
#pragma unroll
  for (int ks=0;ks<4;++ks) hb[ks] = *(const hx8*)(&Hs[c*136 + ks*32 + q*8]);
#pragma unroll
  for (int m2=0;m2<2;++m2) {
    const int mt = w*2 + m2;
    fx4 acc = (fx4){0.f,0.f,0.f,0.f};
#pragma unroll
    for (int ks=0;ks<4;++ks) {
      hx8 aw = *(const hx8*)(Wh2 + ((size_t)(mt*4 + ks)*64 + lane)*8);
      acc = __builtin_amdgcn_mfma_f32_16x16x32_f16(aw, hb[ks], acc, 0,0,0);
    }
    fx4 bias = *(const fx4*)(b2 + mt*16 + 4*q);
    hx4 tv;
#pragma unroll
    for (int i=0;i<4;++i) tv[i] = (half_t)(acc[i] + bias[i]);
    *(hx4*)(T + (size_t)(rb + c)*128 + mt*16 + 4*q) = tv;
  }
}

// ---------------- Kernel 2: flash attention partials (R8 — proven best) ----
// 64-key tiles, nt=2 (0.5 LDS reads/MFMA), grid 512 (2 blocks/CU), deferred
// l-sum, max3 tree, per-wave private Pbuf, 1 barrier/iter, full-iteration
// prefetch, NO setprio.
__global__ __launch_bounds__(256,2) void flash_kernel(
    const half_t* __restrict__ T, const half_t* __restrict__ Zt,
    half_t* __restrict__ Pacc, float* __restrict__ Pm, float* __restrict__ Pl)
{
  __shared__ half_t Tbuf[2][16*512];    // 32 KB
  __shared__ half_t Zbuf[2][16*512];    // 32 KB
  __shared__ half_t Pbuf[4][32*64];     // 16 KB — per-wave private P^T
  const int tid = threadIdx.x;
  const int w = tid >> 6, lane = tid & 63;
  const int q = lane >> 4, c = lane & 15;
  const int bx = blockIdx.x;
  const int qb = bx >> 3, kh = bx & 7;
  const int wrow = qb*128 + w*32;
  const int sw = (c & 7) * 8;

  hx8 bq[2][4];
#pragma unroll
  for (int nt=0;nt<2;++nt)
#pragma unroll
    for (int ks=0;ks<4;++ks)
      bq[nt][ks] = *(const hx8*)(T + (size_t)(wrow + nt*16 + c)*128 + ks*32 + q*8);

  fx4 oacc[8][2];
#pragma unroll
  for (int mtd=0;mtd<8;++mtd)
#pragma unroll
    for (int nt=0;nt<2;++nt) oacc[mtd][nt] = (fx4){0.f,0.f,0.f,0.f};
  float m_run[2] = {-1e30f,-1e30f};
  float l_run[2] = {0.f,0.f};          // per-lane PARTIAL sums (reduced at end)

  const int kbase = kh*1024;
  half_t* Psw = &Pbuf[w][0];           // wave-private 32x64-half P^T

  auto issue_loads = [&](int kt0, int b) {
    if (w < 2) {
#pragma unroll
      for (int i=0;i<8;++i) {
        int f = w*8 + i, mt = f >> 2, ks = f & 3;
        const half_t* gp = T + (size_t)(kt0 + mt*16 + c)*128 + ks*32 + q*8;
        half_t* lp = &Tbuf[b][f*512 + lane*8];
        __builtin_amdgcn_global_load_lds(
            (const __attribute__((address_space(1))) void*)gp,
            (__attribute__((address_space(3))) void*)lp, 16, 0, 0);
      }
    } else {
#pragma unroll
      for (int i=0;i<8;++i) {
        int f2 = (w-2)*8 + i, mtd = f2 >> 1, ks2 = f2 & 1;
        const half_t* gp = Zt + (size_t)(mtd*16 + c)*8192 + kt0 + ks2*32 + q*8;
        half_t* lp = &Zbuf[b][f2*512 + lane*8];
        __builtin_amdgcn_global_load_lds(
            (const __attribute__((address_space(1))) void*)gp,
            (__attribute__((address_space(3))) void*)lp, 16, 0, 0);
      }
    }
  };

  issue_loads(kbase, 0);

  for (int t=0;t<16;++t) {
    const int cur = t & 1;
    __syncthreads();                    // THE barrier: drains own DMA (vmcnt)
                                        // + publishes both buffers of iter t
    half_t* Tcur = Tbuf[cur];
    half_t* Zcur = Zbuf[cur];

    // prefetch t+1 NOW: cur^1 is dead (barrier retired all t-1 reads)
    if (t < 15) issue_loads(kbase + (t+1)*64, cur ^ 1);

    // ---- scores ----
    fx4 sacc[4][2];
#pragma unroll
    for (int mt=0;mt<4;++mt)
#pragma unroll
      for (int nt=0;nt<2;++nt) sacc[mt][nt] = (fx4){0.f,0.f,0.f,0.f};
#pragma unroll
    for (int ks=0;ks<4;++ks)
#pragma unroll
      for (int mt=0;mt<4;++mt) {
        hx8 ak = *(const hx8*)(&Tcur[(mt*4+ks)*512 + lane*8]);
        sacc[mt][0] = __builtin_amdgcn_mfma_f32_16x16x32_f16(ak, bq[0][ks], sacc[mt][0], 0,0,0);
        sacc[mt][1] = __builtin_amdgcn_mfma_f32_16x16x32_f16(ak, bq[1][ks], sacc[mt][1], 0,0,0);
      }

    // ---- online softmax (per-lane partial l; only the MAX is shfl'd) ----
    hx4 pk[2][4];
#pragma unroll
    for (int nt=0;nt<2;++nt) {
      float a0 = fmaxf(fmaxf(sacc[0][nt][0], sacc[0][nt][1]), sacc[0][nt][2]);
      float a1 = fmaxf(fmaxf(sacc[0][nt][3], sacc[1][nt][0]), sacc[1][nt][1]);
      float a2 = fmaxf(fmaxf(sacc[1][nt][2], sacc[1][nt][3]), sacc[2][nt][0]);
      float a3 = fmaxf(fmaxf(sacc[2][nt][1], sacc[2][nt][2]), sacc[2][nt][3]);
      float a4 = fmaxf(fmaxf(sacc[3][nt][0], sacc[3][nt][1]), sacc[3][nt][2]);
      float mx = fmaxf(fmaxf(fmaxf(a0, a1), fmaxf(a2, a3)),
                       fmaxf(a4, sacc[3][nt][3]));
      mx = fmaxf(mx, __shfl_xor(mx, 16, 64));
      mx = fmaxf(mx, __shfl_xor(mx, 32, 64));
      float mnew = fmaxf(m_run[nt], mx);
      float alpha = __builtin_amdgcn_exp2f((m_run[nt]-mnew)*LOG2E);
      m_run[nt] = mnew;
      float nb = mnew*LOG2E;
      float rs = 0.f;
#pragma unroll
      for (int mt=0;mt<4;++mt) {
#pragma unroll
        for (int i=0;i<4;++i) {
          float p = __builtin_amdgcn_exp2f(sacc[mt][nt][i]*LOG2E - nb);
          rs += p;
          pk[nt][mt][i] = (half_t)p;
        }
      }
      l_run[nt] = l_run[nt]*alpha + rs;   // per-lane partial (no shfl here)
#pragma unroll
      for (int mtd=0;mtd<8;++mtd)
#pragma unroll
        for (int i=0;i<4;++i) oacc[mtd][nt][i] *= alpha;
    }

    // P^T into wave-private region (no inter-wave race -> NO barrier)
#pragma unroll
    for (int nt=0;nt<2;++nt)
#pragma unroll
      for (int mt=0;mt<4;++mt)
        *(hx4*)(&Psw[(nt*16 + c)*64 + ((mt*16 + 4*q) ^ sw)]) = pk[nt][mt];

    // ---- PV ----
#pragma unroll
    for (int ks2=0;ks2<2;++ks2) {
      hx8 bp0 = *(const hx8*)(&Psw[(c     )*64 + ((ks2*32 + q*8) ^ sw)]);
      hx8 bp1 = *(const hx8*)(&Psw[(16 + c)*64 + ((ks2*32 + q*8) ^ sw)]);
#pragma unroll
      for (int mtd=0;mtd<8;++mtd) {
        hx8 az = *(const hx8*)(&Zcur[(mtd*2+ks2)*512 + lane*8]);
        oacc[mtd][0] = __builtin_amdgcn_mfma_f32_16x16x32_f16(az, bp0, oacc[mtd][0], 0,0,0);
        oacc[mtd][1] = __builtin_amdgcn_mfma_f32_16x16x32_f16(az, bp1, oacc[mtd][1], 0,0,0);
      }
    }
  }

  // epilogue: reduce the deferred l partials across the 4 lanes per q-row
#pragma unroll
  for (int nt=0;nt<2;++nt) {
    float lf = l_run[nt];
    lf += __shfl_xor(lf, 16, 64);
    lf += __shfl_xor(lf, 32, 64);
    float inv = 1.0f / lf;
    const size_t rowg = (size_t)(bx*128 + w*32 + nt*16 + c);
#pragma unroll
    for (int mtd=0;mtd<8;++mtd) {
      hx4 ov;
#pragma unroll
      for (int i=0;i<4;++i) ov[i] = (half_t)(oacc[mtd][nt][i]*inv);
      *(hx4*)(Pacc + rowg*128 + mtd*16 + 4*q) = ov;
    }
    if (q == 0) {
      Pm[rowg] = m_run[nt];
      Pl[rowg] = lf;
    }
  }
}

// ---------------- Kernel 3: merge NSPLIT key-split partials ----------------
__global__ __launch_bounds__(256) void merge_kernel(
    const float* __restrict__ Z, const half_t* __restrict__ Pacc,
    const float* __restrict__ Pm, const float* __restrict__ Pl,
    float* __restrict__ out)
{
  const int th = blockIdx.x*256 + threadIdx.x;
  const int r = th >> 5, cg = th & 31;
  const int qb = r >> 7, rr = r & 127;
  float mk[NSPLIT], lk[NSPLIT];
  float M = -1e30f;
#pragma unroll
  for (int k=0;k<NSPLIT;++k) {
    int p = qb*NSPLIT + k;
    mk[k] = Pm[p*128 + rr];
    lk[k] = Pl[p*128 + rr];
    M = fmaxf(M, mk[k]);
  }
  float L = 0.f, wk[NSPLIT];
#pragma unroll
  for (int k=0;k<NSPLIT;++k) { wk[k] = lk[k]*__builtin_amdgcn_exp2f((mk[k]-M)*LOG2E); L += wk[k]; }
  float o0=0.f,o1=0.f,o2=0.f,o3=0.f;
#pragma unroll
  for (int k=0;k<NSPLIT;++k) {
    int p = qb*NSPLIT + k;
    hx4 v = *(const hx4*)(Pacc + ((size_t)p*128 + rr)*128 + cg*4);
    o0 += wk[k]*(float)v[0]; o1 += wk[k]*(float)v[1];
    o2 += wk[k]*(float)v[2]; o3 += wk[k]*(float)v[3];
  }
  float invL = 1.0f / L;
  fx4 zv = *(const fx4*)(Z + (size_t)r*128 + cg*4);
  fx4 res;
  res[0] = (1.f-TAU)*zv[0] + TAU*o0*invL;
  res[1] = (1.f-TAU)*zv[1] + TAU*o1*invL;
  res[2] = (1.f-TAU)*zv[2] + TAU*o2*invL;
  res[3] = (1.f-TAU)*zv[3] + TAU*o3*invL;
  *(fx4*)(out + (size_t)r*128 + cg*4) = res;
}

extern "C" void kernel_launch(void* const* d_in, const int* in_sizes, int n_in,
                              void* d_out, int out_size, void* d_ws, size_t ws_size,
                              hipStream_t stream) {
  const float* Z  = (const float*)d_in[0];
  const float* W1 = (const float*)d_in[1];
  const float* b1 = (const float*)d_in[2];
  const float* W2 = (const float*)d_in[3];
  const float* b2 = (const float*)d_in[4];
  float* out = (float*)d_out;

  char* ws = (char*)d_ws;
  const size_t NBLK = 64 * NSPLIT;                                // 512
  half_t* Thi  = (half_t*)(ws);                                   // 2 MB
  half_t* Zth  = (half_t*)(ws + (size_t)2*1024*1024);             // 2 MB
  half_t* Pacc = (half_t*)(ws + (size_t)4*1024*1024);             // 16 MB
  float*  Pm   = (float*)(ws + (size_t)4*1024*1024 + NBLK*128*128*2);
  float*  Pl   = Pm + NBLK*128;
  half_t* Wh1  = (half_t*)(ws + (size_t)20*1024*1024 + 512*1024); // 32 KB
  half_t* Wh2  = Wh1 + 32*64*8;                                   // 32 KB

  hipLaunchKernelGGL(wpack_kernel, dim3(16),   dim3(256), 0, stream, W1, W2, Wh1, Wh2);
  hipLaunchKernelGGL(mlpz_kernel,  dim3(512),  dim3(256), 0, stream, Z, Wh1, b1, Wh2, b2, Thi, Zth);
  hipLaunchKernelGGL(flash_kernel, dim3(NBLK), dim3(256), 0, stream, Thi, Zth, Pacc, Pm, Pl);
  hipLaunchKernelGGL(merge_kernel, dim3(1024), dim3(256), 0, stream, Z, Pacc, Pm, Pl, out);
}